// Round 13
// baseline (170.676 us; speedup 1.0000x reference)
//
#include <hip/hip_runtime.h>

typedef _Float16 half_t;
typedef half_t half2_t __attribute__((ext_vector_type(2)));
typedef half_t half8  __attribute__((ext_vector_type(8)));
typedef unsigned int uint_t;
typedef uint_t uint4v __attribute__((ext_vector_type(4)));
typedef float float4v __attribute__((ext_vector_type(4)));

#define B_  64
#define T_  256
#define F_  16
#define H_  128
#define HP  160   // padded batch stride (320 B): bufA banks 0-15, bufB 16-31 (R11-verified, 0 conflicts)
#define LOG2E 1.44269504f

__device__ __forceinline__ float rcp_(float x)  { return __builtin_amdgcn_rcpf(x); }
__device__ __forceinline__ float sigm2(float x) { return rcp_(1.0f + __builtin_amdgcn_exp2f(x * -LOG2E)); }
__device__ __forceinline__ float tanh2(float x) { return fmaf(rcp_(1.0f + __builtin_amdgcn_exp2f(x * (-2.0f * LOG2E))), 2.0f, -1.0f); }
__device__ __forceinline__ float sigm(float x)  { return rcp_(1.0f + __expf(-x)); }

// Kernel 0: pair batches by window midpoint (R10-verified), then SORT pairs by union
// length desc. Kernel 2 maps bid -> rank 2g+hi so blocks bid and bid+256 (likely
// co-resident partners) carry adjacent-ranked (= similar) unions -> no lone-block tail.
__global__ void make_sched(const int* __restrict__ index, int* __restrict__ pairs) {
    __shared__ int ss[B_], ee[B_], mid[B_], bo[B_];
    __shared__ int pu[32];
    __shared__ int4 praw[32];
    const int t = threadIdx.x;                 // 64
    const int s = index[2 * t], e = index[2 * t + 1];
    ss[t] = s; ee[t] = e; mid[t] = s + e;
    __syncthreads();
    int m = mid[t], r = 0;
    for (int j = 0; j < B_; ++j) r += (mid[j] < m) || (mid[j] == m && j < t);
    bo[r] = t;
    __syncthreads();
    if (t < 32) {
        int bA = bo[2 * t], bB = bo[2 * t + 1];
        int su = min(ss[bA], ss[bB]), eu = max(ee[bA], ee[bB]);
        int4 v;
        v.x = (bA << 8) | bB;
        v.y = (ss[bA] << 16) | ee[bA];
        v.z = (ss[bB] << 16) | ee[bB];
        v.w = (su << 16) | eu;
        praw[t] = v; pu[t] = eu - su;
    }
    __syncthreads();
    if (t < 32) {
        int u = pu[t], r2 = 0;
        for (int j = 0; j < 32; ++j) r2 += (pu[j] > u) || (pu[j] == u && j < t);
        ((int4*)pairs)[r2] = praw[t];
    }
}

// Kernel 1 (verified R7-R12): W_hh [F,4H,H] fp32 -> f16 B-frags for mfma_f32_16x16x32_f16.
// Lane `lane` of tile w8, frag q=m*4+kt, dword e2 holds the f16 pair for
// k = kt*32 + (lane>>4)*8 + 2*e2 (+1), col g = 128*m + 16*w8 + (lane&15).
__global__ void repack_w(const float* __restrict__ whh, uint_t* __restrict__ wt) {
    const int f = blockIdx.x, w = blockIdx.y, tid = threadIdx.x;  // 256 threads
    const int lane = tid & 63, q4 = tid >> 6;
    const int li = lane & 15, lg = lane >> 4;
    const float* base = whh + (size_t)f * 512 * 128;
#pragma unroll
    for (int qq = 0; qq < 4; ++qq) {
        const int qf = q4 * 4 + qq;
        const int m = qf >> 2, kt = qf & 3;
        const int g512 = 128 * m + 16 * w + li;
        uint_t tmp[4];
#pragma unroll
        for (int e2 = 0; e2 < 4; ++e2) {
            int k = kt * 32 + lg * 8 + 2 * e2;
            half2_t h;
            h[0] = (half_t)base[g512 * 128 + k];
            h[1] = (half_t)base[g512 * 128 + k + 1];
            tmp[e2] = __builtin_bit_cast(uint_t, h);
        }
        uint4 out = { tmp[0], tmp[1], tmp[2], tmp[3] };
        ((uint4*)wt)[(((size_t)f * 8 + w) * 16 + qf) * 64 + lane] = out;
    }
}

// Kernel 2: R11 structure (8 waves, 2 chains/block, 512 blocks, 2 blocks/CU) with:
// z4 C-init (-16 v_mov/step), 2x2-deep split MFMA chains (dep depth 4->2), and a
// 3-phase loop (masked / unmasked-middle / masked) dropping the per-step window masks
// where both chains are active.
__global__ __launch_bounds__(512, 4) void lstm_mfma(
    const float* __restrict__ x, const uint_t* __restrict__ wt,
    const float* __restrict__ wih_g, const float* __restrict__ bias_g,
    const int* __restrict__ pairs, float* __restrict__ hout)
{
    __shared__ float xsh[2][T_ + 8];
    __shared__ alignas(16) half_t hbuf[2][2][HP];   // [buf][batch][cell], padded

    const int lo = blockIdx.x & 255, hi = blockIdx.x >> 8;
    const int f = lo & 15, g = lo >> 4;
    const int4 pv = ((const int4*)pairs)[2 * g + hi];
    const int bA = pv.x >> 8, bB = pv.x & 255;
    const int sA = pv.y >> 16, eA = pv.y & 0xffff;
    const int sB = pv.z >> 16, eB = pv.z & 0xffff;
    const int su = pv.w >> 16, eu = pv.w & 0xffff;

    const int tid = threadIdx.x, lane = tid & 63, w = tid >> 6;
    const int li = lane & 15, lg = lane >> 4;
    const int cell = 16 * w + li;
    const int hsel = li >> 3;                 // A-frag row group: 0 -> batch A, 1 -> B
    const int csel = lg >> 1;                 // C row group: 0 -> batch A, 1 -> B

    // ---- opaque weight preload: 16 x global_load_dwordx4 (proven resident R4-R12) ----
    uint4v wr[16];
    {
        const char* ws = (const char*)wt + ((((size_t)f * 8 + w) * 16) * 64 + lane) * 16;
#pragma unroll
        for (int q = 0; q < 16; ++q) {
            unsigned long long a = (unsigned long long)(ws + (size_t)q * 1024);
            asm volatile("global_load_dwordx4 %0, %1, off" : "=v"(wr[q]) : "v"(a));
        }
        asm volatile("s_waitcnt vmcnt(0)");
        __builtin_amdgcn_sched_barrier(0);
    }

    float wih[4], bb4[4];
#pragma unroll
    for (int m = 0; m < 4; ++m) {
        wih[m] = wih_g[f * 512 + 128 * m + cell];
        bb4[m] = bias_g[f * 512 + 128 * m + cell];
    }

    const int myb = csel ? bB : bA;
    const int mys = csel ? sB : sA;
    const int mye = csel ? eB : eA;

    // stage x rows for both batches; zero h buffer 0 (both batches)
    {
        int bb_ = tid >> 8, tt = tid & 255;
        xsh[bb_][tt] = x[((size_t)(bb_ ? bB : bA) * T_ + tt) * F_ + f];
    }
    if (tid < 2 * H_) hbuf[0][tid >> 7][tid & 127] = (half_t)0.0f;

    float cst = 0.0f, hst = 0.0f;
    const float4v z4 = {0.f, 0.f, 0.f, 0.f};
    int pp = 0;
    __syncthreads();

    auto step = [&](int t, bool do_mask) {
        const half_t* hb = &hbuf[pp][hsel][lg * 8];
        half8 a0 = *(const half8*)(hb + 0);
        half8 a1 = *(const half8*)(hb + 32);
        half8 a2 = *(const half8*)(hb + 64);
        half8 a3 = *(const half8*)(hb + 96);
        float xt = xsh[csel][t];

        float gv[4];
#pragma unroll
        for (int m = 0; m < 4; ++m) {
            float4v ca = __builtin_amdgcn_mfma_f32_16x16x32_f16(a0, __builtin_bit_cast(half8, wr[m * 4 + 0]), z4, 0, 0, 0);
            float4v cb = __builtin_amdgcn_mfma_f32_16x16x32_f16(a1, __builtin_bit_cast(half8, wr[m * 4 + 1]), z4, 0, 0, 0);
            ca = __builtin_amdgcn_mfma_f32_16x16x32_f16(a2, __builtin_bit_cast(half8, wr[m * 4 + 2]), ca, 0, 0, 0);
            cb = __builtin_amdgcn_mfma_f32_16x16x32_f16(a3, __builtin_bit_cast(half8, wr[m * 4 + 3]), cb, 0, 0, 0);
            gv[m] = (ca[0] + cb[0]) + fmaf(xt, wih[m], bb4[m]);
        }

        float gi = sigm2(gv[0]);
        float gf = sigm2(gv[1]);
        float gg = tanh2(gv[2]);
        float go = sigm2(gv[3]);
        float cn = fmaf(gf, cst, gi * gg);
        if (do_mask) {
            bool mk = (t >= mys) & (t < mye);
            cst = mk ? cn : cst;
            float hn = go * tanh2(cst);
            hst = mk ? hn : hst;
        } else {
            cst = cn;
            hst = go * tanh2(cst);
        }

        if ((lg & 1) == 0) hbuf[pp ^ 1][csel][cell] = (half_t)hst;
        __syncthreads();
        pp ^= 1;
    };

    int p1 = min(max(sA, sB), eu);
    int p2 = max(min(eA, eB), p1);
    int t = su;
    for (; t < p1; ++t) step(t, true);    // only the earlier-starting chain active
    for (; t < p2; ++t) step(t, false);   // both active: mask-free bulk
    for (; t < eu; ++t) step(t, true);    // only the later-ending chain active

    if ((lg & 1) == 0) hout[((size_t)myb * F_ + f) * H_ + cell] = hst;
}

// Kernel 3: per-batch epilogue: mean over H -> conv3 (pad 1) -> sigmoid gate -> gated fc.
__global__ void epilogue(const float* __restrict__ hout, const float* __restrict__ conv_w,
                         const float* __restrict__ fc_w, const float* __restrict__ fc_b,
                         float* __restrict__ out)
{
    const int b = blockIdx.x, t = threadIdx.x;   // 128 threads
    const int lane = t & 63, wv = t >> 6;
    __shared__ float part[2][16];
    __shared__ float gate_sh[16];

    float hv[16];
#pragma unroll
    for (int f = 0; f < 16; ++f) hv[f] = hout[((size_t)b * 16 + f) * 128 + t];

#pragma unroll
    for (int f = 0; f < 16; ++f) {
        float s = hv[f];
#pragma unroll
        for (int off = 32; off >= 1; off >>= 1) s += __shfl_down(s, off, 64);
        if (lane == 0) part[wv][f] = s;
    }
    __syncthreads();
    if (t < 16) gate_sh[t] = (part[0][t] + part[1][t]) * (1.0f / 128.0f);
    __syncthreads();
    float gate = 0.0f;
    if (t < 16) {
        float l  = (t > 0)  ? gate_sh[t - 1] : 0.0f;
        float mi = gate_sh[t];
        float r  = (t < 15) ? gate_sh[t + 1] : 0.0f;
        gate = sigm(fmaf(l, conv_w[0], fmaf(mi, conv_w[1], r * conv_w[2])));
    }
    __syncthreads();
    if (t < 16) gate_sh[t] = gate;
    __syncthreads();

    float acc0 = 0.0f, acc1 = 0.0f;
    const float2* fw2 = (const float2*)fc_w;
#pragma unroll
    for (int f = 0; f < 16; ++f) {
        float hg = hv[f] * gate_sh[f];
        float2 w2 = fw2[f * 128 + t];
        acc0 = fmaf(hg, w2.x, acc0);
        acc1 = fmaf(hg, w2.y, acc1);
    }
#pragma unroll
    for (int off = 32; off >= 1; off >>= 1) {
        acc0 += __shfl_down(acc0, off, 64);
        acc1 += __shfl_down(acc1, off, 64);
    }
    if (lane == 0) { part[wv][0] = acc0; part[wv][1] = acc1; }
    __syncthreads();
    if (t == 0) {
        out[b * 2 + 0] = part[0][0] + part[1][0] + fc_b[0];
        out[b * 2 + 1] = part[0][1] + part[1][1] + fc_b[1];
    }
}

extern "C" void kernel_launch(void* const* d_in, const int* in_sizes, int n_in,
                              void* d_out, int out_size, void* d_ws, size_t ws_size,
                              hipStream_t stream) {
    const float* x      = (const float*)d_in[0];
    const int*   index  = (const int*)  d_in[1];
    const float* W_ih   = (const float*)d_in[2];
    const float* W_hh   = (const float*)d_in[3];
    const float* bias   = (const float*)d_in[4];
    const float* conv_w = (const float*)d_in[5];
    const float* fc_w   = (const float*)d_in[6];
    const float* fc_b   = (const float*)d_in[7];
    float* out = (float*)d_out;

    uint_t* wt    = (uint_t*)d_ws;                                     // 2 MB
    float*  hout  = (float*)((char*)d_ws + 2 * 1024 * 1024);           // 512 KB
    int*    pairs = (int*)((char*)d_ws + 2 * 1024 * 1024 + 512 * 1024); // 512 B

    make_sched<<<1, 64, 0, stream>>>(index, pairs);
    repack_w<<<dim3(F_, 8), 256, 0, stream>>>(W_hh, wt);
    lstm_mfma<<<512, 512, 0, stream>>>(x, wt, W_ih, bias, pairs, hout);
    epilogue<<<B_, 128, 0, stream>>>(hout, conv_w, fc_w, fc_b, out);
}

// Round 14
// 128.016 us; speedup vs baseline: 1.3332x; 1.3332x over previous
//
#include <hip/hip_runtime.h>

typedef _Float16 half_t;
typedef half_t half2_t __attribute__((ext_vector_type(2)));
typedef half_t half8  __attribute__((ext_vector_type(8)));
typedef unsigned int uint_t;
typedef uint_t uint4v __attribute__((ext_vector_type(4)));
typedef float float4v __attribute__((ext_vector_type(4)));

#define B_  64
#define T_  256
#define F_  16
#define H_  128
#define HP  160   // padded batch stride (320 B): bufA banks 0-15, bufB 16-31 (R11-verified, 0 conflicts)
#define LOG2E 1.44269504f

__device__ __forceinline__ float rcp_(float x)  { return __builtin_amdgcn_rcpf(x); }
__device__ __forceinline__ float sigm2(float x) { return rcp_(1.0f + __builtin_amdgcn_exp2f(x * -LOG2E)); }
__device__ __forceinline__ float tanh2(float x) { return fmaf(rcp_(1.0f + __builtin_amdgcn_exp2f(x * (-2.0f * LOG2E))), 2.0f, -1.0f); }
__device__ __forceinline__ float sigm(float x)  { return rcp_(1.0f + __expf(-x)); }

// Kernel 0: pair batches by window midpoint (R10-verified), then sort pairs by union
// desc. Kernel 2 maps the two likely co-resident blocks of a CU (bid, bid+256) to
// ranks g and 31-g: longest pairs with shortest -> the short partner drains early and
// the long (critical) block runs SOLO at ~2x per-wave issue rate (R13 proved the
// adjacent-rank placement does the opposite and costs 24%).
__global__ void make_sched(const int* __restrict__ index, int* __restrict__ pairs) {
    __shared__ int ss[B_], ee[B_], mid[B_], bo[B_];
    __shared__ int pu[32];
    __shared__ int4 praw[32];
    const int t = threadIdx.x;                 // 64
    const int s = index[2 * t], e = index[2 * t + 1];
    ss[t] = s; ee[t] = e; mid[t] = s + e;
    __syncthreads();
    int m = mid[t], r = 0;
    for (int j = 0; j < B_; ++j) r += (mid[j] < m) || (mid[j] == m && j < t);
    bo[r] = t;
    __syncthreads();
    if (t < 32) {
        int bA = bo[2 * t], bB = bo[2 * t + 1];
        int su = min(ss[bA], ss[bB]), eu = max(ee[bA], ee[bB]);
        int4 v;
        v.x = (bA << 8) | bB;
        v.y = (ss[bA] << 16) | ee[bA];
        v.z = (ss[bB] << 16) | ee[bB];
        v.w = (su << 16) | eu;
        praw[t] = v; pu[t] = eu - su;
    }
    __syncthreads();
    if (t < 32) {
        int u = pu[t], r2 = 0;
        for (int j = 0; j < 32; ++j) r2 += (pu[j] > u) || (pu[j] == u && j < t);
        ((int4*)pairs)[r2] = praw[t];
    }
}

// Kernel 1 (verified R7-R13): W_hh [F,4H,H] fp32 -> f16 B-frags for mfma_f32_16x16x32_f16.
// Lane `lane` of tile w8, frag q=m*4+kt, dword e2 holds the f16 pair for
// k = kt*32 + (lane>>4)*8 + 2*e2 (+1), col g = 128*m + 16*w8 + (lane&15).
__global__ void repack_w(const float* __restrict__ whh, uint_t* __restrict__ wt) {
    const int f = blockIdx.x, w = blockIdx.y, tid = threadIdx.x;  // 256 threads
    const int lane = tid & 63, q4 = tid >> 6;
    const int li = lane & 15, lg = lane >> 4;
    const float* base = whh + (size_t)f * 512 * 128;
#pragma unroll
    for (int qq = 0; qq < 4; ++qq) {
        const int qf = q4 * 4 + qq;
        const int m = qf >> 2, kt = qf & 3;
        const int g512 = 128 * m + 16 * w + li;
        uint_t tmp[4];
#pragma unroll
        for (int e2 = 0; e2 < 4; ++e2) {
            int k = kt * 32 + lg * 8 + 2 * e2;
            half2_t h;
            h[0] = (half_t)base[g512 * 128 + k];
            h[1] = (half_t)base[g512 * 128 + k + 1];
            tmp[e2] = __builtin_bit_cast(uint_t, h);
        }
        uint4 out = { tmp[0], tmp[1], tmp[2], tmp[3] };
        ((uint4*)wt)[(((size_t)f * 8 + w) * 16 + qf) * 64 + lane] = out;
    }
}

// Kernel 2: exact R11 body (136 us best: 8 waves, 2 chains/block via paired A-rows,
// single 4-deep MFMA chain with iv C-init, single always-masked loop, padded hbuf).
// Only the pair-rank mapping changed: rank = hi ? 31-g : g (anti-balanced placement).
__global__ __launch_bounds__(512, 4) void lstm_mfma(
    const float* __restrict__ x, const uint_t* __restrict__ wt,
    const float* __restrict__ wih_g, const float* __restrict__ bias_g,
    const int* __restrict__ pairs, float* __restrict__ hout)
{
    __shared__ float xsh[2][T_ + 8];
    __shared__ alignas(16) half_t hbuf[2][2][HP];   // [buf][batch][cell], padded

    const int lo = blockIdx.x & 255, hi = blockIdx.x >> 8;
    const int f = lo & 15, g = lo >> 4;
    const int rank = hi ? (31 - g) : g;             // long pairs with short on one CU
    const int4 pv = ((const int4*)pairs)[rank];
    const int bA = pv.x >> 8, bB = pv.x & 255;
    const int sA = pv.y >> 16, eA = pv.y & 0xffff;
    const int sB = pv.z >> 16, eB = pv.z & 0xffff;
    const int su = pv.w >> 16, eu = pv.w & 0xffff;

    const int tid = threadIdx.x, lane = tid & 63, w = tid >> 6;
    const int li = lane & 15, lg = lane >> 4;
    const int cell = 16 * w + li;
    const int hsel = li >> 3;                 // A-frag row group: 0 -> batch A, 1 -> B
    const int csel = lg >> 1;                 // C row group: 0 -> batch A, 1 -> B

    // ---- opaque weight preload: 16 x global_load_dwordx4 (proven resident R4-R13) ----
    uint4v wr[16];
    {
        const char* ws = (const char*)wt + ((((size_t)f * 8 + w) * 16) * 64 + lane) * 16;
#pragma unroll
        for (int q = 0; q < 16; ++q) {
            unsigned long long a = (unsigned long long)(ws + (size_t)q * 1024);
            asm volatile("global_load_dwordx4 %0, %1, off" : "=v"(wr[q]) : "v"(a));
        }
        asm volatile("s_waitcnt vmcnt(0)");
        __builtin_amdgcn_sched_barrier(0);
    }

    float wih[4], bb4[4];
#pragma unroll
    for (int m = 0; m < 4; ++m) {
        wih[m] = wih_g[f * 512 + 128 * m + cell];
        bb4[m] = bias_g[f * 512 + 128 * m + cell];
    }

    const int myb = csel ? bB : bA;
    const int mys = csel ? sB : sA;
    const int mye = csel ? eB : eA;

    // stage x rows for both batches; zero h buffer 0 (both batches)
    {
        int bb_ = tid >> 8, tt = tid & 255;
        xsh[bb_][tt] = x[((size_t)(bb_ ? bB : bA) * T_ + tt) * F_ + f];
    }
    if (tid < 2 * H_) hbuf[0][tid >> 7][tid & 127] = (half_t)0.0f;

    float cst = 0.0f, hst = 0.0f;
    int pp = 0;
    __syncthreads();

    for (int t = su; t < eu; ++t) {
        // A-frags: broadcast reads of current h for this lane's A-row batch
        const half_t* hb = &hbuf[pp][hsel][lg * 8];
        half8 a0 = *(const half8*)(hb + 0);
        half8 a1 = *(const half8*)(hb + 32);
        half8 a2 = *(const half8*)(hb + 64);
        half8 a3 = *(const half8*)(hb + 96);
        float xt = xsh[csel][t];

        float gv[4];
#pragma unroll
        for (int m = 0; m < 4; ++m) {
            float iv = fmaf(xt, wih[m], bb4[m]);
            float4v ci = { iv, iv, iv, iv };   // single 4-deep chain (R11-proven best)
            ci = __builtin_amdgcn_mfma_f32_16x16x32_f16(a0, __builtin_bit_cast(half8, wr[m * 4 + 0]), ci, 0, 0, 0);
            ci = __builtin_amdgcn_mfma_f32_16x16x32_f16(a1, __builtin_bit_cast(half8, wr[m * 4 + 1]), ci, 0, 0, 0);
            ci = __builtin_amdgcn_mfma_f32_16x16x32_f16(a2, __builtin_bit_cast(half8, wr[m * 4 + 2]), ci, 0, 0, 0);
            ci = __builtin_amdgcn_mfma_f32_16x16x32_f16(a3, __builtin_bit_cast(half8, wr[m * 4 + 3]), ci, 0, 0, 0);
            gv[m] = ci[0];                     // reg 0: row lg*4 -> this lane's batch
        }

        float gi = sigm2(gv[0]);
        float gf = sigm2(gv[1]);
        float gg = tanh2(gv[2]);
        float go = sigm2(gv[3]);
        float cn = fmaf(gf, cst, gi * gg);
        bool mk = (t >= mys) & (t < mye);
        cst = mk ? cn : cst;
        float hn = go * tanh2(cst);
        hst = mk ? hn : hst;

        if ((lg & 1) == 0) hbuf[pp ^ 1][csel][cell] = (half_t)hst;
        __syncthreads();
        pp ^= 1;
    }

    if ((lg & 1) == 0) hout[((size_t)myb * F_ + f) * H_ + cell] = hst;
}

// Kernel 3: per-batch epilogue: mean over H -> conv3 (pad 1) -> sigmoid gate -> gated fc.
__global__ void epilogue(const float* __restrict__ hout, const float* __restrict__ conv_w,
                         const float* __restrict__ fc_w, const float* __restrict__ fc_b,
                         float* __restrict__ out)
{
    const int b = blockIdx.x, t = threadIdx.x;   // 128 threads
    const int lane = t & 63, wv = t >> 6;
    __shared__ float part[2][16];
    __shared__ float gate_sh[16];

    float hv[16];
#pragma unroll
    for (int f = 0; f < 16; ++f) hv[f] = hout[((size_t)b * 16 + f) * 128 + t];

#pragma unroll
    for (int f = 0; f < 16; ++f) {
        float s = hv[f];
#pragma unroll
        for (int off = 32; off >= 1; off >>= 1) s += __shfl_down(s, off, 64);
        if (lane == 0) part[wv][f] = s;
    }
    __syncthreads();
    if (t < 16) gate_sh[t] = (part[0][t] + part[1][t]) * (1.0f / 128.0f);
    __syncthreads();
    float gate = 0.0f;
    if (t < 16) {
        float l  = (t > 0)  ? gate_sh[t - 1] : 0.0f;
        float mi = gate_sh[t];
        float r  = (t < 15) ? gate_sh[t + 1] : 0.0f;
        gate = sigm(fmaf(l, conv_w[0], fmaf(mi, conv_w[1], r * conv_w[2])));
    }
    __syncthreads();
    if (t < 16) gate_sh[t] = gate;
    __syncthreads();

    float acc0 = 0.0f, acc1 = 0.0f;
    const float2* fw2 = (const float2*)fc_w;
#pragma unroll
    for (int f = 0; f < 16; ++f) {
        float hg = hv[f] * gate_sh[f];
        float2 w2 = fw2[f * 128 + t];
        acc0 = fmaf(hg, w2.x, acc0);
        acc1 = fmaf(hg, w2.y, acc1);
    }
#pragma unroll
    for (int off = 32; off >= 1; off >>= 1) {
        acc0 += __shfl_down(acc0, off, 64);
        acc1 += __shfl_down(acc1, off, 64);
    }
    if (lane == 0) { part[wv][0] = acc0; part[wv][1] = acc1; }
    __syncthreads();
    if (t == 0) {
        out[b * 2 + 0] = part[0][0] + part[1][0] + fc_b[0];
        out[b * 2 + 1] = part[0][1] + part[1][1] + fc_b[1];
    }
}

extern "C" void kernel_launch(void* const* d_in, const int* in_sizes, int n_in,
                              void* d_out, int out_size, void* d_ws, size_t ws_size,
                              hipStream_t stream) {
    const float* x      = (const float*)d_in[0];
    const int*   index  = (const int*)  d_in[1];
    const float* W_ih   = (const float*)d_in[2];
    const float* W_hh   = (const float*)d_in[3];
    const float* bias   = (const float*)d_in[4];
    const float* conv_w = (const float*)d_in[5];
    const float* fc_w   = (const float*)d_in[6];
    const float* fc_b   = (const float*)d_in[7];
    float* out = (float*)d_out;

    uint_t* wt    = (uint_t*)d_ws;                                     // 2 MB
    float*  hout  = (float*)((char*)d_ws + 2 * 1024 * 1024);           // 512 KB
    int*    pairs = (int*)((char*)d_ws + 2 * 1024 * 1024 + 512 * 1024); // 512 B

    make_sched<<<1, 64, 0, stream>>>(index, pairs);
    repack_w<<<dim3(F_, 8), 256, 0, stream>>>(W_hh, wt);
    lstm_mfma<<<512, 512, 0, stream>>>(x, wt, W_ih, bias, pairs, hout);
    epilogue<<<B_, 128, 0, stream>>>(hout, conv_w, fc_w, fc_b, out);
}

// Round 15
// 127.496 us; speedup vs baseline: 1.3387x; 1.0041x over previous
//
#include <hip/hip_runtime.h>

typedef _Float16 half_t;
typedef half_t half2_t __attribute__((ext_vector_type(2)));
typedef half_t half8  __attribute__((ext_vector_type(8)));
typedef unsigned int uint_t;
typedef uint_t uint4v __attribute__((ext_vector_type(4)));
typedef float float4v __attribute__((ext_vector_type(4)));

#define B_  64
#define T_  256
#define F_  16
#define H_  128
#define HP  160   // padded batch stride (320 B): bufA banks 0-15, bufB 16-31 (R11-verified, 0 conflicts)
#define LOG2E 1.44269504f

__device__ __forceinline__ float rcp_(float x)  { return __builtin_amdgcn_rcpf(x); }
__device__ __forceinline__ float sigm2(float x) { return rcp_(1.0f + __builtin_amdgcn_exp2f(x * -LOG2E)); }
__device__ __forceinline__ float tanh2(float x) { return fmaf(rcp_(1.0f + __builtin_amdgcn_exp2f(x * (-2.0f * LOG2E))), 2.0f, -1.0f); }
__device__ __forceinline__ float sigm(float x)  { return rcp_(1.0f + __expf(-x)); }

// Kernel 0: pair batches by window midpoint (R10-verified), sort pairs by union desc.
// Kernel 2 maps co-resident blocks (bid, bid+256) to ranks g and 31-g (R14-verified:
// long+short on one CU -> short partner drains, long block runs solo; 136->128 us).
__global__ void make_sched(const int* __restrict__ index, int* __restrict__ pairs) {
    __shared__ int ss[B_], ee[B_], mid[B_], bo[B_];
    __shared__ int pu[32];
    __shared__ int4 praw[32];
    const int t = threadIdx.x;                 // 64
    const int s = index[2 * t], e = index[2 * t + 1];
    ss[t] = s; ee[t] = e; mid[t] = s + e;
    __syncthreads();
    int m = mid[t], r = 0;
    for (int j = 0; j < B_; ++j) r += (mid[j] < m) || (mid[j] == m && j < t);
    bo[r] = t;
    __syncthreads();
    if (t < 32) {
        int bA = bo[2 * t], bB = bo[2 * t + 1];
        int su = min(ss[bA], ss[bB]), eu = max(ee[bA], ee[bB]);
        int4 v;
        v.x = (bA << 8) | bB;
        v.y = (ss[bA] << 16) | ee[bA];
        v.z = (ss[bB] << 16) | ee[bB];
        v.w = (su << 16) | eu;
        praw[t] = v; pu[t] = eu - su;
    }
    __syncthreads();
    if (t < 32) {
        int u = pu[t], r2 = 0;
        for (int j = 0; j < 32; ++j) r2 += (pu[j] > u) || (pu[j] == u && j < t);
        ((int4*)pairs)[r2] = praw[t];
    }
}

// Kernel 1 (verified R7-R14): W_hh [F,4H,H] fp32 -> f16 B-frags for mfma_f32_16x16x32_f16.
// Lane `lane` of tile w8, frag q=m*4+kt, dword e2 holds the f16 pair for
// k = kt*32 + (lane>>4)*8 + 2*e2 (+1), col g = 128*m + 16*w8 + (lane&15).
__global__ void repack_w(const float* __restrict__ whh, uint_t* __restrict__ wt) {
    const int f = blockIdx.x, w = blockIdx.y, tid = threadIdx.x;  // 256 threads
    const int lane = tid & 63, q4 = tid >> 6;
    const int li = lane & 15, lg = lane >> 4;
    const float* base = whh + (size_t)f * 512 * 128;
#pragma unroll
    for (int qq = 0; qq < 4; ++qq) {
        const int qf = q4 * 4 + qq;
        const int m = qf >> 2, kt = qf & 3;
        const int g512 = 128 * m + 16 * w + li;
        uint_t tmp[4];
#pragma unroll
        for (int e2 = 0; e2 < 4; ++e2) {
            int k = kt * 32 + lg * 8 + 2 * e2;
            half2_t h;
            h[0] = (half_t)base[g512 * 128 + k];
            h[1] = (half_t)base[g512 * 128 + k + 1];
            tmp[e2] = __builtin_bit_cast(uint_t, h);
        }
        uint4 out = { tmp[0], tmp[1], tmp[2], tmp[3] };
        ((uint4*)wt)[(((size_t)f * 8 + w) * 16 + qf) * 64 + lane] = out;
    }
}

// Kernel 2: R14 placement (anti-balanced rank = hi ? 31-g : g) + R13 body trims
// (z4 C-init -16 v_mov/step, 2x2-deep split MFMA chains, 3-phase loop eliding the
// window masks in the both-chains-active bulk). All pieces independently verified.
__global__ __launch_bounds__(512, 4) void lstm_mfma(
    const float* __restrict__ x, const uint_t* __restrict__ wt,
    const float* __restrict__ wih_g, const float* __restrict__ bias_g,
    const int* __restrict__ pairs, float* __restrict__ hout)
{
    __shared__ float xsh[2][T_ + 8];
    __shared__ alignas(16) half_t hbuf[2][2][HP];   // [buf][batch][cell], padded

    const int lo = blockIdx.x & 255, hi = blockIdx.x >> 8;
    const int f = lo & 15, g = lo >> 4;
    const int rank = hi ? (31 - g) : g;             // long pairs with short on one CU
    const int4 pv = ((const int4*)pairs)[rank];
    const int bA = pv.x >> 8, bB = pv.x & 255;
    const int sA = pv.y >> 16, eA = pv.y & 0xffff;
    const int sB = pv.z >> 16, eB = pv.z & 0xffff;
    const int su = pv.w >> 16, eu = pv.w & 0xffff;

    const int tid = threadIdx.x, lane = tid & 63, w = tid >> 6;
    const int li = lane & 15, lg = lane >> 4;
    const int cell = 16 * w + li;
    const int hsel = li >> 3;                 // A-frag row group: 0 -> batch A, 1 -> B
    const int csel = lg >> 1;                 // C row group: 0 -> batch A, 1 -> B

    // ---- opaque weight preload: 16 x global_load_dwordx4 (proven resident R4-R14) ----
    uint4v wr[16];
    {
        const char* ws = (const char*)wt + ((((size_t)f * 8 + w) * 16) * 64 + lane) * 16;
#pragma unroll
        for (int q = 0; q < 16; ++q) {
            unsigned long long a = (unsigned long long)(ws + (size_t)q * 1024);
            asm volatile("global_load_dwordx4 %0, %1, off" : "=v"(wr[q]) : "v"(a));
        }
        asm volatile("s_waitcnt vmcnt(0)");
        __builtin_amdgcn_sched_barrier(0);
    }

    float wih[4], bb4[4];
#pragma unroll
    for (int m = 0; m < 4; ++m) {
        wih[m] = wih_g[f * 512 + 128 * m + cell];
        bb4[m] = bias_g[f * 512 + 128 * m + cell];
    }

    const int myb = csel ? bB : bA;
    const int mys = csel ? sB : sA;
    const int mye = csel ? eB : eA;

    // stage x rows for both batches; zero h buffer 0 (both batches)
    {
        int bb_ = tid >> 8, tt = tid & 255;
        xsh[bb_][tt] = x[((size_t)(bb_ ? bB : bA) * T_ + tt) * F_ + f];
    }
    if (tid < 2 * H_) hbuf[0][tid >> 7][tid & 127] = (half_t)0.0f;

    float cst = 0.0f, hst = 0.0f;
    const float4v z4 = {0.f, 0.f, 0.f, 0.f};
    int pp = 0;
    __syncthreads();

    auto step = [&](int t, bool do_mask) {
        const half_t* hb = &hbuf[pp][hsel][lg * 8];
        half8 a0 = *(const half8*)(hb + 0);
        half8 a1 = *(const half8*)(hb + 32);
        half8 a2 = *(const half8*)(hb + 64);
        half8 a3 = *(const half8*)(hb + 96);
        float xt = xsh[csel][t];

        float gv[4];
#pragma unroll
        for (int m = 0; m < 4; ++m) {
            float4v ca = __builtin_amdgcn_mfma_f32_16x16x32_f16(a0, __builtin_bit_cast(half8, wr[m * 4 + 0]), z4, 0, 0, 0);
            float4v cb = __builtin_amdgcn_mfma_f32_16x16x32_f16(a1, __builtin_bit_cast(half8, wr[m * 4 + 1]), z4, 0, 0, 0);
            ca = __builtin_amdgcn_mfma_f32_16x16x32_f16(a2, __builtin_bit_cast(half8, wr[m * 4 + 2]), ca, 0, 0, 0);
            cb = __builtin_amdgcn_mfma_f32_16x16x32_f16(a3, __builtin_bit_cast(half8, wr[m * 4 + 3]), cb, 0, 0, 0);
            gv[m] = (ca[0] + cb[0]) + fmaf(xt, wih[m], bb4[m]);
        }

        float gi = sigm2(gv[0]);
        float gf = sigm2(gv[1]);
        float gg = tanh2(gv[2]);
        float go = sigm2(gv[3]);
        float cn = fmaf(gf, cst, gi * gg);
        if (do_mask) {
            bool mk = (t >= mys) & (t < mye);
            cst = mk ? cn : cst;
            float hn = go * tanh2(cst);
            hst = mk ? hn : hst;
        } else {
            cst = cn;
            hst = go * tanh2(cst);
        }

        if ((lg & 1) == 0) hbuf[pp ^ 1][csel][cell] = (half_t)hst;
        __syncthreads();
        pp ^= 1;
    };

    int p1 = min(max(sA, sB), eu);
    int p2 = max(min(eA, eB), p1);
    int t = su;
    for (; t < p1; ++t) step(t, true);    // only the earlier-starting chain active
    for (; t < p2; ++t) step(t, false);   // both active: mask-free bulk
    for (; t < eu; ++t) step(t, true);    // only the later-ending chain active

    if ((lg & 1) == 0) hout[((size_t)myb * F_ + f) * H_ + cell] = hst;
}

// Kernel 3: per-batch epilogue: mean over H -> conv3 (pad 1) -> sigmoid gate -> gated fc.
__global__ void epilogue(const float* __restrict__ hout, const float* __restrict__ conv_w,
                         const float* __restrict__ fc_w, const float* __restrict__ fc_b,
                         float* __restrict__ out)
{
    const int b = blockIdx.x, t = threadIdx.x;   // 128 threads
    const int lane = t & 63, wv = t >> 6;
    __shared__ float part[2][16];
    __shared__ float gate_sh[16];

    float hv[16];
#pragma unroll
    for (int f = 0; f < 16; ++f) hv[f] = hout[((size_t)b * 16 + f) * 128 + t];

#pragma unroll
    for (int f = 0; f < 16; ++f) {
        float s = hv[f];
#pragma unroll
        for (int off = 32; off >= 1; off >>= 1) s += __shfl_down(s, off, 64);
        if (lane == 0) part[wv][f] = s;
    }
    __syncthreads();
    if (t < 16) gate_sh[t] = (part[0][t] + part[1][t]) * (1.0f / 128.0f);
    __syncthreads();
    float gate = 0.0f;
    if (t < 16) {
        float l  = (t > 0)  ? gate_sh[t - 1] : 0.0f;
        float mi = gate_sh[t];
        float r  = (t < 15) ? gate_sh[t + 1] : 0.0f;
        gate = sigm(fmaf(l, conv_w[0], fmaf(mi, conv_w[1], r * conv_w[2])));
    }
    __syncthreads();
    if (t < 16) gate_sh[t] = gate;
    __syncthreads();

    float acc0 = 0.0f, acc1 = 0.0f;
    const float2* fw2 = (const float2*)fc_w;
#pragma unroll
    for (int f = 0; f < 16; ++f) {
        float hg = hv[f] * gate_sh[f];
        float2 w2 = fw2[f * 128 + t];
        acc0 = fmaf(hg, w2.x, acc0);
        acc1 = fmaf(hg, w2.y, acc1);
    }
#pragma unroll
    for (int off = 32; off >= 1; off >>= 1) {
        acc0 += __shfl_down(acc0, off, 64);
        acc1 += __shfl_down(acc1, off, 64);
    }
    if (lane == 0) { part[wv][0] = acc0; part[wv][1] = acc1; }
    __syncthreads();
    if (t == 0) {
        out[b * 2 + 0] = part[0][0] + part[1][0] + fc_b[0];
        out[b * 2 + 1] = part[0][1] + part[1][1] + fc_b[1];
    }
}

extern "C" void kernel_launch(void* const* d_in, const int* in_sizes, int n_in,
                              void* d_out, int out_size, void* d_ws, size_t ws_size,
                              hipStream_t stream) {
    const float* x      = (const float*)d_in[0];
    const int*   index  = (const int*)  d_in[1];
    const float* W_ih   = (const float*)d_in[2];
    const float* W_hh   = (const float*)d_in[3];
    const float* bias   = (const float*)d_in[4];
    const float* conv_w = (const float*)d_in[5];
    const float* fc_w   = (const float*)d_in[6];
    const float* fc_b   = (const float*)d_in[7];
    float* out = (float*)d_out;

    uint_t* wt    = (uint_t*)d_ws;                                     // 2 MB
    float*  hout  = (float*)((char*)d_ws + 2 * 1024 * 1024);           // 512 KB
    int*    pairs = (int*)((char*)d_ws + 2 * 1024 * 1024 + 512 * 1024); // 512 B

    make_sched<<<1, 64, 0, stream>>>(index, pairs);
    repack_w<<<dim3(F_, 8), 256, 0, stream>>>(W_hh, wt);
    lstm_mfma<<<512, 512, 0, stream>>>(x, wt, W_ih, bias, pairs, hout);
    epilogue<<<B_, 128, 0, stream>>>(hout, conv_w, fc_w, fc_b, out);
}

// Round 16
// 122.495 us; speedup vs baseline: 1.3933x; 1.0408x over previous
//
#include <hip/hip_runtime.h>

typedef _Float16 half_t;
typedef half_t half2_t __attribute__((ext_vector_type(2)));
typedef half_t half8  __attribute__((ext_vector_type(8)));
typedef unsigned int uint_t;
typedef uint_t uint4v __attribute__((ext_vector_type(4)));
typedef float float4v __attribute__((ext_vector_type(4)));

#define B_  64
#define T_  256
#define F_  16
#define H_  128
#define HQ  144   // quad hbuf batch stride in f16 (288 B = 72 dwords, 72%32=8 -> 2-way banks, free)
#define XQ  264   // xsh batch stride in f32 (264%32=8 -> 4 xt broadcasts on distinct banks)
#define LOG2E 1.44269504f

__device__ __forceinline__ float rcp_(float x)  { return __builtin_amdgcn_rcpf(x); }
__device__ __forceinline__ float sigm2(float x) { return rcp_(1.0f + __builtin_amdgcn_exp2f(x * -LOG2E)); }
__device__ __forceinline__ float tanh2(float x) { return fmaf(rcp_(1.0f + __builtin_amdgcn_exp2f(x * (-2.0f * LOG2E))), 2.0f, -1.0f); }
__device__ __forceinline__ float sigm(float x)  { return rcp_(1.0f + __expf(-x)); }

// Kernel 0: rank batches by window midpoint; quads = 4 consecutive ranks (similar
// windows -> tight quad union). gmeta[r] = {b, s, e, 0}; guni[q] = {su, eu}, q=0..15.
__global__ void make_sched(const int* __restrict__ index, int* __restrict__ gmeta,
                           int* __restrict__ guni) {
    __shared__ int mid[B_], oB[B_], oS[B_], oE[B_];
    const int t = threadIdx.x;                 // 64
    const int s = index[2 * t], e = index[2 * t + 1];
    mid[t] = s + e;
    __syncthreads();
    int m = mid[t], r = 0;
    for (int j = 0; j < B_; ++j) r += (mid[j] < m) || (mid[j] == m && j < t);
    oB[r] = t; oS[r] = s; oE[r] = e;
    __syncthreads();
    int4 v; v.x = oB[t]; v.y = oS[t]; v.z = oE[t]; v.w = 0;
    ((int4*)gmeta)[t] = v;
    if (t < 16) {
        int su = 1 << 30, eu = 0;
        for (int j = 0; j < 4; ++j) { su = min(su, oS[4 * t + j]); eu = max(eu, oE[4 * t + j]); }
        guni[2 * t] = su; guni[2 * t + 1] = eu;
    }
}

// Kernel 1 (verified R7-R15): W_hh [F,4H,H] fp32 -> f16 B-frags for mfma_f32_16x16x32_f16.
// Lane `lane` of tile w8, frag q=m*4+kt, dword e2 holds the f16 pair for
// k = kt*32 + (lane>>4)*8 + 2*e2 (+1), col g = 128*m + 16*w8 + (lane&15).
__global__ void repack_w(const float* __restrict__ whh, uint_t* __restrict__ wt) {
    const int f = blockIdx.x, w = blockIdx.y, tid = threadIdx.x;  // 256 threads
    const int lane = tid & 63, q4 = tid >> 6;
    const int li = lane & 15, lg = lane >> 4;
    const float* base = whh + (size_t)f * 512 * 128;
#pragma unroll
    for (int qq = 0; qq < 4; ++qq) {
        const int qf = q4 * 4 + qq;
        const int m = qf >> 2, kt = qf & 3;
        const int g512 = 128 * m + 16 * w + li;
        uint_t tmp[4];
#pragma unroll
        for (int e2 = 0; e2 < 4; ++e2) {
            int k = kt * 32 + lg * 8 + 2 * e2;
            half2_t h;
            h[0] = (half_t)base[g512 * 128 + k];
            h[1] = (half_t)base[g512 * 128 + k + 1];
            tmp[e2] = __builtin_bit_cast(uint_t, h);
        }
        uint4 out = { tmp[0], tmp[1], tmp[2], tmp[3] };
        ((uint4*)wt)[(((size_t)f * 8 + w) * 16 + qf) * 64 + lane] = out;
    }
}

// Kernel 2: QUAD packing. 256 blocks = 16 f x 16 quads; 8 waves; 1 block/CU, single
// dispatch round. A rows 4c..4c+3 = batch c's h (lane's A-row = li -> reads batch
// li>>2); C row 4*lg reg 0 -> lane (li,lg) owns cell 16w+li of batch lg. All 64 lanes
// unique work: same 16 MFMA/wave-step serve FOUR chains (2x less work per chain than
// R15). hbuf stride 288 B / xsh stride 264 f32 keep all broadcasts <=2-way (free).
__global__ __launch_bounds__(512, 4) void lstm_mfma(
    const float* __restrict__ x, const uint_t* __restrict__ wt,
    const float* __restrict__ wih_g, const float* __restrict__ bias_g,
    const int* __restrict__ gmeta, const int* __restrict__ guni,
    float* __restrict__ hout)
{
    __shared__ float xsh[4][XQ];
    __shared__ alignas(16) half_t hbuf[2][4][HQ];   // [buf][batch][cell]
    __shared__ int bid4[4];

    const int f = blockIdx.x & 15, q = blockIdx.x >> 4;
    const int tid = threadIdx.x, lane = tid & 63, w = tid >> 6;
    const int li = lane & 15, lg = lane >> 4;
    const int ar = li >> 2;                   // A-row batch slot this lane reads
    const int cell = 16 * w + li;

    // ---- opaque weight preload: 16 x global_load_dwordx4 (proven resident R4-R15) ----
    uint4v wr[16];
    {
        const char* ws = (const char*)wt + ((((size_t)f * 8 + w) * 16) * 64 + lane) * 16;
#pragma unroll
        for (int p = 0; p < 16; ++p) {
            unsigned long long a = (unsigned long long)(ws + (size_t)p * 1024);
            asm volatile("global_load_dwordx4 %0, %1, off" : "=v"(wr[p]) : "v"(a));
        }
        asm volatile("s_waitcnt vmcnt(0)");
        __builtin_amdgcn_sched_barrier(0);
    }

    // per-lane compute batch = lg
    const int4 mymeta = ((const int4*)gmeta)[q * 4 + lg];
    const int bmy = mymeta.x, mys = mymeta.y, mye = mymeta.z;
    if (tid < 4) bid4[tid] = ((const int4*)gmeta)[q * 4 + tid].x;
    const int su = guni[2 * q], eu = guni[2 * q + 1];

    float wih[4], bb4[4];
#pragma unroll
    for (int m = 0; m < 4; ++m) {
        wih[m] = wih_g[f * 512 + 128 * m + cell];
        bb4[m] = bias_g[f * 512 + 128 * m + cell];
    }
    __syncthreads();                          // bid4 visible

    // stage x rows for 4 batches (2 per thread); zero h buffer 0 (one entry per thread)
#pragma unroll
    for (int j = 0; j < 2; ++j) {
        int idx = tid + 512 * j;
        int c = idx >> 8, tt = idx & 255;
        xsh[c][tt] = x[((size_t)bid4[c] * T_ + tt) * F_ + f];
    }
    hbuf[0][tid >> 7][tid & 127] = (half_t)0.0f;

    float cst = 0.0f, hst = 0.0f;
    const float4v z4 = {0.f, 0.f, 0.f, 0.f};
    int pp = 0;
    __syncthreads();

    for (int t = su; t < eu; ++t) {
        // A-frags: 4 b128 broadcast reads of batch `ar`'s h (16 distinct addrs/wave,
        // 2-way banks by the 288 B stride)
        const half_t* hb = &hbuf[pp][ar][lg * 8];
        half8 a0 = *(const half8*)(hb + 0);
        half8 a1 = *(const half8*)(hb + 32);
        half8 a2 = *(const half8*)(hb + 64);
        half8 a3 = *(const half8*)(hb + 96);
        float xt = xsh[lg][t];

        float gv[4];
#pragma unroll
        for (int m = 0; m < 4; ++m) {
            float4v ca = __builtin_amdgcn_mfma_f32_16x16x32_f16(a0, __builtin_bit_cast(half8, wr[m * 4 + 0]), z4, 0, 0, 0);
            float4v cb = __builtin_amdgcn_mfma_f32_16x16x32_f16(a1, __builtin_bit_cast(half8, wr[m * 4 + 1]), z4, 0, 0, 0);
            ca = __builtin_amdgcn_mfma_f32_16x16x32_f16(a2, __builtin_bit_cast(half8, wr[m * 4 + 2]), ca, 0, 0, 0);
            cb = __builtin_amdgcn_mfma_f32_16x16x32_f16(a3, __builtin_bit_cast(half8, wr[m * 4 + 3]), cb, 0, 0, 0);
            gv[m] = (ca[0] + cb[0]) + fmaf(xt, wih[m], bb4[m]);   // C row 4*lg -> batch lg
        }

        float gi = sigm2(gv[0]);
        float gf = sigm2(gv[1]);
        float gg = tanh2(gv[2]);
        float go = sigm2(gv[3]);
        float cn = fmaf(gf, cst, gi * gg);
        bool mk = (t >= mys) & (t < mye);
        cst = mk ? cn : cst;
        float hn = go * tanh2(cst);
        hst = mk ? hn : hst;

        hbuf[pp ^ 1][lg][cell] = (half_t)hst;   // all 64 lanes: one b16 each, 32 dwords
        __syncthreads();
        pp ^= 1;
    }

    hout[((size_t)bmy * F_ + f) * H_ + cell] = hst;
}

// Kernel 3: per-batch epilogue: mean over H -> conv3 (pad 1) -> sigmoid gate -> gated fc.
__global__ void epilogue(const float* __restrict__ hout, const float* __restrict__ conv_w,
                         const float* __restrict__ fc_w, const float* __restrict__ fc_b,
                         float* __restrict__ out)
{
    const int b = blockIdx.x, t = threadIdx.x;   // 128 threads
    const int lane = t & 63, wv = t >> 6;
    __shared__ float part[2][16];
    __shared__ float gate_sh[16];

    float hv[16];
#pragma unroll
    for (int f = 0; f < 16; ++f) hv[f] = hout[((size_t)b * 16 + f) * 128 + t];

#pragma unroll
    for (int f = 0; f < 16; ++f) {
        float s = hv[f];
#pragma unroll
        for (int off = 32; off >= 1; off >>= 1) s += __shfl_down(s, off, 64);
        if (lane == 0) part[wv][f] = s;
    }
    __syncthreads();
    if (t < 16) gate_sh[t] = (part[0][t] + part[1][t]) * (1.0f / 128.0f);
    __syncthreads();
    float gate = 0.0f;
    if (t < 16) {
        float l  = (t > 0)  ? gate_sh[t - 1] : 0.0f;
        float mi = gate_sh[t];
        float r  = (t < 15) ? gate_sh[t + 1] : 0.0f;
        gate = sigm(fmaf(l, conv_w[0], fmaf(mi, conv_w[1], r * conv_w[2])));
    }
    __syncthreads();
    if (t < 16) gate_sh[t] = gate;
    __syncthreads();

    float acc0 = 0.0f, acc1 = 0.0f;
    const float2* fw2 = (const float2*)fc_w;
#pragma unroll
    for (int f = 0; f < 16; ++f) {
        float hg = hv[f] * gate_sh[f];
        float2 w2 = fw2[f * 128 + t];
        acc0 = fmaf(hg, w2.x, acc0);
        acc1 = fmaf(hg, w2.y, acc1);
    }
#pragma unroll
    for (int off = 32; off >= 1; off >>= 1) {
        acc0 += __shfl_down(acc0, off, 64);
        acc1 += __shfl_down(acc1, off, 64);
    }
    if (lane == 0) { part[wv][0] = acc0; part[wv][1] = acc1; }
    __syncthreads();
    if (t == 0) {
        out[b * 2 + 0] = part[0][0] + part[1][0] + fc_b[0];
        out[b * 2 + 1] = part[0][1] + part[1][1] + fc_b[1];
    }
}

extern "C" void kernel_launch(void* const* d_in, const int* in_sizes, int n_in,
                              void* d_out, int out_size, void* d_ws, size_t ws_size,
                              hipStream_t stream) {
    const float* x      = (const float*)d_in[0];
    const int*   index  = (const int*)  d_in[1];
    const float* W_ih   = (const float*)d_in[2];
    const float* W_hh   = (const float*)d_in[3];
    const float* bias   = (const float*)d_in[4];
    const float* conv_w = (const float*)d_in[5];
    const float* fc_w   = (const float*)d_in[6];
    const float* fc_b   = (const float*)d_in[7];
    float* out = (float*)d_out;

    uint_t* wt    = (uint_t*)d_ws;                                      // 2 MB
    float*  hout  = (float*)((char*)d_ws + 2 * 1024 * 1024);            // 512 KB
    int*    gmeta = (int*)((char*)d_ws + 2 * 1024 * 1024 + 512 * 1024); // 1 KB
    int*    guni  = (int*)((char*)d_ws + 2 * 1024 * 1024 + 512 * 1024 + 1024); // 128 B

    make_sched<<<1, 64, 0, stream>>>(index, gmeta, guni);
    repack_w<<<dim3(F_, 8), 256, 0, stream>>>(W_hh, wt);
    lstm_mfma<<<256, 512, 0, stream>>>(x, wt, W_ih, bias, gmeta, guni, hout);
    epilogue<<<B_, 128, 0, stream>>>(hout, conv_w, fc_w, fc_b, out);
}

// Round 17
// 119.585 us; speedup vs baseline: 1.4272x; 1.0243x over previous
//
#include <hip/hip_runtime.h>

typedef _Float16 half_t;
typedef half_t half2_t __attribute__((ext_vector_type(2)));
typedef half_t half8  __attribute__((ext_vector_type(8)));
typedef unsigned int uint_t;
typedef uint_t uint4v __attribute__((ext_vector_type(4)));
typedef float float4v __attribute__((ext_vector_type(4)));

#define B_  64
#define T_  256
#define F_  16
#define H_  128
#define HQ  144   // quad hbuf batch stride in f16 (288 B = 72 dwords, 72%32=8 -> 2-way banks, free)
#define XQ  264   // xsh batch stride in f32 (264%32=8 -> 4 xt broadcasts on distinct banks)
#define LOG2E 1.44269504f

__device__ __forceinline__ float rcp_(float x)  { return __builtin_amdgcn_rcpf(x); }
__device__ __forceinline__ float sigm2(float x) { return rcp_(1.0f + __builtin_amdgcn_exp2f(x * -LOG2E)); }
__device__ __forceinline__ float tanh2(float x) { return fmaf(rcp_(1.0f + __builtin_amdgcn_exp2f(x * (-2.0f * LOG2E))), 2.0f, -1.0f); }
__device__ __forceinline__ float sigm(float x)  { return rcp_(1.0f + __expf(-x)); }

// Kernel 1 (repack verified R7-R16) + FUSED scheduler (block (0,0) threads 0-63:
// rank batches by window midpoint, quads = 4 consecutive ranks -> gmeta/guni).
// W_hh [F,4H,H] fp32 -> f16 B-frags for mfma_f32_16x16x32_f16: lane `lane` of tile w8,
// frag q=m*4+kt, dword e2 = f16 pair for k=kt*32+(lane>>4)*8+2*e2, col g=128m+16w8+(lane&15).
__global__ void repack_w(const float* __restrict__ whh, const int* __restrict__ index,
                         uint_t* __restrict__ wt, int* __restrict__ gmeta,
                         int* __restrict__ guni) {
    __shared__ int sM[B_], sS[B_], sE[B_], sB[B_], sS2[B_], sE2[B_];
    const int f = blockIdx.x, w = blockIdx.y, tid = threadIdx.x;  // 256 threads
    const bool sb = (f == 0) && (w == 0);

    if (sb && tid < B_) {
        int s = index[2 * tid], e = index[2 * tid + 1];
        sS[tid] = s; sE[tid] = e; sM[tid] = s + e;
    }
    __syncthreads();
    if (sb && tid < B_) {
        int m = sM[tid], r = 0;
        for (int j = 0; j < B_; ++j) r += (sM[j] < m) || (sM[j] == m && j < tid);
        sB[r] = tid; sS2[r] = sS[tid]; sE2[r] = sE[tid];
    }
    __syncthreads();
    if (sb && tid < B_) {
        int4 v; v.x = sB[tid]; v.y = sS2[tid]; v.z = sE2[tid]; v.w = 0;
        ((int4*)gmeta)[tid] = v;
        if (tid < 16) {
            int su = 1 << 30, eu = 0;
            for (int j = 0; j < 4; ++j) { su = min(su, sS2[4 * tid + j]); eu = max(eu, sE2[4 * tid + j]); }
            guni[2 * tid] = su; guni[2 * tid + 1] = eu;
        }
    }

    const int lane = tid & 63, q4 = tid >> 6;
    const int li = lane & 15, lg = lane >> 4;
    const float* base = whh + (size_t)f * 512 * 128;
#pragma unroll
    for (int qq = 0; qq < 4; ++qq) {
        const int qf = q4 * 4 + qq;
        const int m = qf >> 2, kt = qf & 3;
        const int g512 = 128 * m + 16 * w + li;
        uint_t tmp[4];
#pragma unroll
        for (int e2 = 0; e2 < 4; ++e2) {
            int k = kt * 32 + lg * 8 + 2 * e2;
            half2_t h;
            h[0] = (half_t)base[g512 * 128 + k];
            h[1] = (half_t)base[g512 * 128 + k + 1];
            tmp[e2] = __builtin_bit_cast(uint_t, h);
        }
        uint4 out = { tmp[0], tmp[1], tmp[2], tmp[3] };
        ((uint4*)wt)[(((size_t)f * 8 + w) * 16 + qf) * 64 + lane] = out;
    }
}

// Kernel 2: QUAD packing (R16 structure, 118 us): 256 blocks = 16 f x 16 quads, 8 waves,
// 1 block/CU. A rows 4c..4c+3 = batch c's h; lane (li,lg) owns cell 16w+li of batch lg.
// NEW: recurrence unrolled by 2 with compile-time src/dst hbuf pointers -> the pp-flip
// address math is off the serial ring (barrier->ds_read->MFMA->nonlin->write ring is
// the measured ~1050 cyc/step floor; R13/R15 proved issue & chain-depth trims flat).
__global__ __launch_bounds__(512, 4) void lstm_mfma(
    const float* __restrict__ x, const uint_t* __restrict__ wt,
    const float* __restrict__ wih_g, const float* __restrict__ bias_g,
    const int* __restrict__ gmeta, const int* __restrict__ guni,
    float* __restrict__ hout)
{
    __shared__ float xsh[4][XQ];
    __shared__ alignas(16) half_t hbuf[2][4][HQ];   // [buf][batch][cell]
    __shared__ int bid4[4];

    const int f = blockIdx.x & 15, q = blockIdx.x >> 4;
    const int tid = threadIdx.x, lane = tid & 63, w = tid >> 6;
    const int li = lane & 15, lg = lane >> 4;
    const int ar = li >> 2;                   // A-row batch slot this lane reads
    const int cell = 16 * w + li;

    // ---- opaque weight preload: 16 x global_load_dwordx4 (proven resident R4-R16) ----
    uint4v wr[16];
    {
        const char* ws = (const char*)wt + ((((size_t)f * 8 + w) * 16) * 64 + lane) * 16;
#pragma unroll
        for (int p = 0; p < 16; ++p) {
            unsigned long long a = (unsigned long long)(ws + (size_t)p * 1024);
            asm volatile("global_load_dwordx4 %0, %1, off" : "=v"(wr[p]) : "v"(a));
        }
        asm volatile("s_waitcnt vmcnt(0)");
        __builtin_amdgcn_sched_barrier(0);
    }

    // per-lane compute batch = lg
    const int4 mymeta = ((const int4*)gmeta)[q * 4 + lg];
    const int bmy = mymeta.x, mys = mymeta.y, mye = mymeta.z;
    if (tid < 4) bid4[tid] = ((const int4*)gmeta)[q * 4 + tid].x;
    const int su = guni[2 * q], eu = guni[2 * q + 1];

    float wih[4], bb4[4];
#pragma unroll
    for (int m = 0; m < 4; ++m) {
        wih[m] = wih_g[f * 512 + 128 * m + cell];
        bb4[m] = bias_g[f * 512 + 128 * m + cell];
    }
    __syncthreads();                          // bid4 visible

    // stage x rows for 4 batches (2 per thread); zero h buffer 0
#pragma unroll
    for (int j = 0; j < 2; ++j) {
        int idx = tid + 512 * j;
        int c = idx >> 8, tt = idx & 255;
        xsh[c][tt] = x[((size_t)bid4[c] * T_ + tt) * F_ + f];
    }
    hbuf[0][tid >> 7][tid & 127] = (half_t)0.0f;

    float cst = 0.0f, hst = 0.0f;
    const float4v z4 = {0.f, 0.f, 0.f, 0.f};
    __syncthreads();

    // compile-time buffer pointers (no pp arithmetic on the ring)
    const half_t* rd0 = &hbuf[0][ar][lg * 8];
    const half_t* rd1 = &hbuf[1][ar][lg * 8];
    half_t* wr0 = &hbuf[1][lg][cell];         // dst when reading buf0
    half_t* wr1 = &hbuf[0][lg][cell];         // dst when reading buf1

    auto STEP = [&](const half_t* rd, half_t* wrp, int t) {
        half8 a0 = *(const half8*)(rd + 0);
        half8 a1 = *(const half8*)(rd + 32);
        half8 a2 = *(const half8*)(rd + 64);
        half8 a3 = *(const half8*)(rd + 96);
        float xt = xsh[lg][t];

        float gv[4];
#pragma unroll
        for (int m = 0; m < 4; ++m) {
            float4v ca = __builtin_amdgcn_mfma_f32_16x16x32_f16(a0, __builtin_bit_cast(half8, wr[m * 4 + 0]), z4, 0, 0, 0);
            float4v cb = __builtin_amdgcn_mfma_f32_16x16x32_f16(a1, __builtin_bit_cast(half8, wr[m * 4 + 1]), z4, 0, 0, 0);
            ca = __builtin_amdgcn_mfma_f32_16x16x32_f16(a2, __builtin_bit_cast(half8, wr[m * 4 + 2]), ca, 0, 0, 0);
            cb = __builtin_amdgcn_mfma_f32_16x16x32_f16(a3, __builtin_bit_cast(half8, wr[m * 4 + 3]), cb, 0, 0, 0);
            gv[m] = (ca[0] + cb[0]) + fmaf(xt, wih[m], bb4[m]);   // C row 4*lg -> batch lg
        }

        float gi = sigm2(gv[0]);
        float gf = sigm2(gv[1]);
        float gg = tanh2(gv[2]);
        float go = sigm2(gv[3]);
        float cn = fmaf(gf, cst, gi * gg);
        bool mk = (t >= mys) & (t < mye);
        cst = mk ? cn : cst;
        float hn = go * tanh2(cst);
        hst = mk ? hn : hst;

        wrp[0] = (half_t)hst;                 // all 64 lanes: one b16 each, 2-way banks
        __syncthreads();
    };

    int t = su;
    while (t < eu) {
        STEP(rd0, wr0, t); ++t;
        if (t >= eu) break;
        STEP(rd1, wr1, t); ++t;
    }

    hout[((size_t)bmy * F_ + f) * H_ + cell] = hst;
}

// Kernel 3: per-batch epilogue: mean over H -> conv3 (pad 1) -> sigmoid gate -> gated fc.
__global__ void epilogue(const float* __restrict__ hout, const float* __restrict__ conv_w,
                         const float* __restrict__ fc_w, const float* __restrict__ fc_b,
                         float* __restrict__ out)
{
    const int b = blockIdx.x, t = threadIdx.x;   // 128 threads
    const int lane = t & 63, wv = t >> 6;
    __shared__ float part[2][16];
    __shared__ float gate_sh[16];

    float hv[16];
#pragma unroll
    for (int f = 0; f < 16; ++f) hv[f] = hout[((size_t)b * 16 + f) * 128 + t];

#pragma unroll
    for (int f = 0; f < 16; ++f) {
        float s = hv[f];
#pragma unroll
        for (int off = 32; off >= 1; off >>= 1) s += __shfl_down(s, off, 64);
        if (lane == 0) part[wv][f] = s;
    }
    __syncthreads();
    if (t < 16) gate_sh[t] = (part[0][t] + part[1][t]) * (1.0f / 128.0f);
    __syncthreads();
    float gate = 0.0f;
    if (t < 16) {
        float l  = (t > 0)  ? gate_sh[t - 1] : 0.0f;
        float mi = gate_sh[t];
        float r  = (t < 15) ? gate_sh[t + 1] : 0.0f;
        gate = sigm(fmaf(l, conv_w[0], fmaf(mi, conv_w[1], r * conv_w[2])));
    }
    __syncthreads();
    if (t < 16) gate_sh[t] = gate;
    __syncthreads();

    float acc0 = 0.0f, acc1 = 0.0f;
    const float2* fw2 = (const float2*)fc_w;
#pragma unroll
    for (int f = 0; f < 16; ++f) {
        float hg = hv[f] * gate_sh[f];
        float2 w2 = fw2[f * 128 + t];
        acc0 = fmaf(hg, w2.x, acc0);
        acc1 = fmaf(hg, w2.y, acc1);
    }
#pragma unroll
    for (int off = 32; off >= 1; off >>= 1) {
        acc0 += __shfl_down(acc0, off, 64);
        acc1 += __shfl_down(acc1, off, 64);
    }
    if (lane == 0) { part[wv][0] = acc0; part[wv][1] = acc1; }
    __syncthreads();
    if (t == 0) {
        out[b * 2 + 0] = part[0][0] + part[1][0] + fc_b[0];
        out[b * 2 + 1] = part[0][1] + part[1][1] + fc_b[1];
    }
}

extern "C" void kernel_launch(void* const* d_in, const int* in_sizes, int n_in,
                              void* d_out, int out_size, void* d_ws, size_t ws_size,
                              hipStream_t stream) {
    const float* x      = (const float*)d_in[0];
    const int*   index  = (const int*)  d_in[1];
    const float* W_ih   = (const float*)d_in[2];
    const float* W_hh   = (const float*)d_in[3];
    const float* bias   = (const float*)d_in[4];
    const float* conv_w = (const float*)d_in[5];
    const float* fc_w   = (const float*)d_in[6];
    const float* fc_b   = (const float*)d_in[7];
    float* out = (float*)d_out;

    uint_t* wt    = (uint_t*)d_ws;                                      // 2 MB
    float*  hout  = (float*)((char*)d_ws + 2 * 1024 * 1024);            // 512 KB
    int*    gmeta = (int*)((char*)d_ws + 2 * 1024 * 1024 + 512 * 1024); // 1 KB
    int*    guni  = (int*)((char*)d_ws + 2 * 1024 * 1024 + 512 * 1024 + 1024); // 128 B

    repack_w<<<dim3(F_, 8), 256, 0, stream>>>(W_hh, index, wt, gmeta, guni);
    lstm_mfma<<<256, 512, 0, stream>>>(x, wt, W_ih, bias, gmeta, guni, hout);
    epilogue<<<B_, 128, 0, stream>>>(hout, conv_w, fc_w, fc_b, out);
}